// Round 24
// baseline (81.190 us; speedup 1.0000x reference)
//
#include <hip/hip_runtime.h>
#include <hip/hip_bf16.h>
#include <math.h>

#define NN    8
#define HH    64
#define WW    64
#define HW    4096
#define NHW   32768
#define DALL  384     // 256 value + 112 om + 16 pad
#define EPSBN 1e-5f
#define GFRONT 25344              // guard shorts before VO (>= 65*384=24960)
#define GBACK  50688              // guard shorts after VO (>= 49792)
#define VOELEMS 12582912          // NHW*384

typedef __attribute__((ext_vector_type(8))) short short8v;
typedef __attribute__((ext_vector_type(4))) float f32x4;
typedef __attribute__((ext_vector_type(2))) _Float16 half2v;
typedef __attribute__((ext_vector_type(8))) _Float16 half8v;
typedef __attribute__((ext_vector_type(2))) __fp16 fp16x2v;   // cvt_pkrtz return type

__device__ __forceinline__ unsigned short f2h(float f) {
    union { _Float16 h; unsigned short u; } c; c.h = (_Float16)f; return c.u;
}
__device__ __forceinline__ float h2f(unsigned short u) {
    union { unsigned short u; _Float16 h; } c; c.u = u; return (float)c.h;
}

// Workspace layout (bytes):
//  VOg    [GFRONT + NHW*384 + GBACK] f16 @ 0    (25317888)   VO = VOg+GFRONT
//  Wallh  [384][256] f16   @ 25317888   (196608)
//  Wouth  [256][256] f16   @ 25514496   (131072)
//  ball   [384] f32        @ 25645568   (1536)
//  bout   [256] f32        @ 25647104   (1024)

// ---------------- prep: fold weights (f32 math, f16 output) + guard zeroing ----------------
__global__ __launch_bounds__(256)
void prep_kernel(const float* __restrict__ cv1_w, const float* __restrict__ cv1_b,
                 const float* __restrict__ value_w, const float* __restrict__ value_b,
                 const float* __restrict__ dw_w, const float* __restrict__ dw_b,
                 const float* __restrict__ om_w, const float* __restrict__ om_b,
                 const float* __restrict__ out_w, const float* __restrict__ cv2_w,
                 const float* __restrict__ bn_g, const float* __restrict__ bn_b,
                 const float* __restrict__ bn_m, const float* __restrict__ bn_v,
                 unsigned short* __restrict__ Wallh, float* __restrict__ ball,
                 unsigned short* __restrict__ Wouth, float* __restrict__ bout,
                 unsigned short* __restrict__ VOg)
{
    int job = blockIdx.x * 256 + threadIdx.x;
    if (job < 65536) {                          // Wv = value_w @ cv1_w
        int d = job >> 8, cc = job & 255;
        float s0=0.f, s1=0.f, s2=0.f, s3=0.f;
        for (int e = 0; e < 256; e += 4) {
            float4 wv = *reinterpret_cast<const float4*>(&value_w[d*256+e]);
            s0 = fmaf(wv.x, cv1_w[(e+0)*256+cc], s0);
            s1 = fmaf(wv.y, cv1_w[(e+1)*256+cc], s1);
            s2 = fmaf(wv.z, cv1_w[(e+2)*256+cc], s2);
            s3 = fmaf(wv.w, cv1_w[(e+3)*256+cc], s3);
        }
        Wallh[job] = f2h((s0+s1)+(s2+s3));
    } else if (job < 94208) {                   // Wom = om_w.diag(dw_w) @ cv1_w
        int idx = job - 65536;
        int o = idx >> 8, cc = idx & 255;
        float s0=0.f, s1=0.f, s2=0.f, s3=0.f;
        for (int e = 0; e < 256; e += 4) {
            float4 wv = *reinterpret_cast<const float4*>(&om_w[o*256+e]);
            float4 dv = *reinterpret_cast<const float4*>(&dw_w[e]);
            s0 = fmaf(wv.x*dv.x, cv1_w[(e+0)*256+cc], s0);
            s1 = fmaf(wv.y*dv.y, cv1_w[(e+1)*256+cc], s1);
            s2 = fmaf(wv.z*dv.z, cv1_w[(e+2)*256+cc], s2);
            s3 = fmaf(wv.w*dv.w, cv1_w[(e+3)*256+cc], s3);
        }
        Wallh[job] = f2h((s0+s1)+(s2+s3));
    } else if (job < 98304) {                   // pad rows 368..383
        Wallh[job] = 0;
    } else if (job < 163840) {                  // Wout = diag(s) cv2_w @ out_w
        int idx = job - 98304;
        int d = idx >> 8, cc = idx & 255;
        float s0=0.f, s1=0.f, s2=0.f, s3=0.f;
        for (int e = 0; e < 256; e += 4) {
            float4 wv = *reinterpret_cast<const float4*>(&cv2_w[d*256+e]);
            s0 = fmaf(wv.x, out_w[(e+0)*256+cc], s0);
            s1 = fmaf(wv.y, out_w[(e+1)*256+cc], s1);
            s2 = fmaf(wv.z, out_w[(e+2)*256+cc], s2);
            s3 = fmaf(wv.w, out_w[(e+3)*256+cc], s3);
        }
        float sc = bn_g[d] * rsqrtf(bn_v[d] + EPSBN);
        Wouth[idx] = f2h(((s0+s1)+(s2+s3)) * sc);
    } else if (job < 164096) {                  // bv
        int d = job - 163840;
        float s = value_b[d];
        for (int e = 0; e < 256; ++e) s = fmaf(value_w[d*256+e], cv1_b[e], s);
        ball[d] = s;
    } else if (job < 164208) {                  // bom
        int o = job - 164096;
        float s = om_b[o];
        for (int e = 0; e < 256; ++e)
            s = fmaf(om_w[o*256+e], fmaf(dw_w[e], cv1_b[e], dw_b[e]), s);
        ball[256 + o] = s;
    } else if (job < 164224) {                  // ball pad
        ball[368 + job - 164208] = 0.f;
    } else if (job < 164480) {                  // bout
        int d = job - 164224;
        float sc = bn_g[d] * rsqrtf(bn_v[d] + EPSBN);
        bout[d] = fmaf(-bn_m[d], sc, bn_b[d]);
    } else if (job < 173984) {                  // zero VO guard margins (every call)
        int i = job - 164480;                   // 0..9503
        size_t dst = (i < 3168) ? (size_t)i * 8
                                : (size_t)GFRONT + VOELEMS + (size_t)(i - 3168) * 8;
        short8v z = {};
        *reinterpret_cast<short8v*>(&VOg[dst]) = z;
    }
}

// ---------------- GEMM1 (fused x-transpose): VO = f16(x)^T @ Wallh^T + ball ----------------
// C-tile restaged through LDS: scalar 2B global stores (64/thread) replaced by
// 8 coalesced short8 stores via the (dead after MFMA) ABs tile.
__global__ __launch_bounds__(256)
void gemm_vo_kernel(const float* __restrict__ x, const unsigned short* __restrict__ Wallh,
                    const float* __restrict__ ball, unsigned short* __restrict__ VO)
{
    __shared__ unsigned short ABs[16384];     // As = ABs, Bs = ABs+8192; epilogue: 128x128 f16
    unsigned short* As = ABs;
    unsigned short* Bs = ABs + 8192;
    int t = threadIdx.x;
    int m0 = blockIdx.y * 128;   // pixel tile
    int n0 = blockIdx.x * 128;   // output-channel tile
    int nimg = m0 >> 12, hw0 = m0 & 4095;
    int lane = t & 63;
    int wv = t >> 6;
    int wr = wv >> 1, wc = wv & 1;
    int r_l = lane & 15, kg_l = lane >> 4;
    int ci = t >> 6;             // c-chunk (16 ch) for A staging
    int l  = t & 63;             // row-pair for A staging

    const float* xbase = x + (size_t)(nimg * 256) * 4096 + hw0;

    f32x4 acc[4][4] = {};

    for (int kt = 0; kt < 4; ++kt) {
        int c0 = kt * 64;
        float2 val[16];
        #pragma unroll
        for (int i = 0; i < 16; ++i)
            val[i] = *reinterpret_cast<const float2*>(
                &xbase[(size_t)(c0 + ci*16 + i) * 4096 + 2*l]);
        __syncthreads();   // prior MFMA reads done before overwrite
        #pragma unroll
        for (int rsel = 0; rsel < 2; ++rsel) {
            int row = 2*l + rsel;
            #pragma unroll
            for (int kgi = 0; kgi < 2; ++kgi) {
                int kg = ci*2 + kgi;
                union { short8v s; fp16x2v h[4]; } su;
                #pragma unroll
                for (int j = 0; j < 8; j += 2) {
                    float a = rsel ? val[kgi*8+j].y   : val[kgi*8+j].x;
                    float b = rsel ? val[kgi*8+j+1].y : val[kgi*8+j+1].x;
                    su.h[j>>1] = __builtin_amdgcn_cvt_pkrtz(a, b);
                }
                *reinterpret_cast<short8v*>(&As[row*64 + ((kg ^ (row & 7)) << 3)]) = su.s;
            }
        }
        #pragma unroll
        for (int i = 0; i < 4; ++i) {
            int idx = t + i*256;
            int row = idx >> 3, kg = idx & 7;
            *reinterpret_cast<short8v*>(&Bs[row*64 + ((kg ^ (row & 7)) << 3)]) =
                *reinterpret_cast<const short8v*>(&Wallh[(size_t)(n0 + row)*256 + c0 + kg*8]);
        }
        __syncthreads();
        #pragma unroll
        for (int ks = 0; ks < 2; ++ks) {
            half8v af[4], bfr[4];
            #pragma unroll
            for (int m = 0; m < 4; ++m) {
                int row = wr*64 + m*16 + r_l;
                af[m] = *reinterpret_cast<const half8v*>(
                    &As[row*64 + (((ks*4 + kg_l) ^ (row & 7)) << 3)]);
            }
            #pragma unroll
            for (int n = 0; n < 4; ++n) {
                int row = wc*64 + n*16 + r_l;
                bfr[n] = *reinterpret_cast<const half8v*>(
                    &Bs[row*64 + (((ks*4 + kg_l) ^ (row & 7)) << 3)]);
            }
            #pragma unroll
            for (int m = 0; m < 4; ++m)
                #pragma unroll
                for (int n = 0; n < 4; ++n)
                    acc[m][n] = __builtin_amdgcn_mfma_f32_16x16x32_f16(af[m], bfr[n], acc[m][n], 0, 0, 0);
        }
    }

    // ---- epilogue: stage C into ABs (swizzled), then coalesced short8 stores ----
    __syncthreads();   // MFMA reads of As/Bs complete
    #pragma unroll
    for (int n = 0; n < 4; ++n) {
        int dcol = wc*64 + n*16 + r_l;
        float bb = ball[n0 + dcol];
        #pragma unroll
        for (int m = 0; m < 4; ++m) {
            int rowb = wr*64 + m*16 + (kg_l << 2);
            #pragma unroll
            for (int r = 0; r < 4; ++r) {
                int row = rowb + r;
                ABs[row*128 + (dcol ^ ((row & 3) << 4))] = f2h(acc[m][n][r] + bb);
            }
        }
    }
    __syncthreads();
    {
        int row = t >> 1, half = t & 1;
        int sw = (row & 3) << 4;
        unsigned short* dst = &VO[(size_t)(m0 + row)*384 + n0 + half*64];
        #pragma unroll
        for (int c8 = 0; c8 < 8; ++c8) {
            int col = half*64 + c8*8;
            *reinterpret_cast<short8v*>(dst + c8*8) =
                *reinterpret_cast<const short8v*>(&ABs[row*128 + (col ^ sw)]);
        }
    }
}

// ---------------- fused DCNv4 + GEMM2: out = SiLU(Wout @ dcn(VO)^T + bout) ----------------
// Tap-table stores the precomputed corner OFFSET (no per-lane clamps):
// phase-0 clamps pxf/pyf to [-1,64] (equivalent to reference masking), OOB
// corner weights are exactly 0, and VO guard margins make the reads safe.
__global__ __launch_bounds__(512, 4)
void dcn_gemm_kernel(const unsigned short* __restrict__ VO,
                     const unsigned short* __restrict__ Wouth,
                     const float* __restrict__ bout, float* __restrict__ out)
{
    __shared__ unsigned short y_lds[16384];   // 32 KB: 4 sections x [64px][64k], swizzled
    __shared__ int u_buf_i[8192];             // 32 KB: tap tables | phase2 As
    int*   xyt = u_buf_i;                                    // [2304] corner element offset
    uint2* wt  = reinterpret_cast<uint2*>(u_buf_i + 2304);   // [2304] 4 f16 weights
    unsigned short* As = reinterpret_cast<unsigned short*>(u_buf_i);

    int t = threadIdx.x;
    int bid = blockIdx.x;                     // 512 blocks = 8 XCD x 64
    int logical = ((bid & 7) << 6) + (bid >> 3);   // image == XCD
    int p0 = logical * 64;
    int nimg = p0 >> 12;
    int hw0 = p0 & 4095;
    int h = hw0 >> 6;                         // single image row; w == px

    const unsigned short* vimg = VO + (size_t)nimg * (HW * (size_t)DALL);

    // ---- phase 0: build tap tables (setup math computed once per tap) ----
    for (int i = t; i < 2304; i += 512) {
        int px = i / 36;
        int rem = i - px * 36;
        int g = rem / 9;
        int k = rem - g * 9;
        const unsigned short* ob = vimg + (size_t)(hw0 + px) * DALL + 256 + g * 27;
        float dxo = h2f(ob[2*k]), dyo = h2f(ob[2*k+1]), m = h2f(ob[18+k]);
        float pxf = fminf(fmaxf((float)(px + (k % 3) - 1) + dxo, -1.f), 64.f);
        float pyf = fminf(fmaxf((float)(h  + (k / 3) - 1) + dyo, -1.f), 64.f);
        float x0f = floorf(pxf), y0f = floorf(pyf);
        float fx = pxf - x0f, fy = pyf - y0f;
        int x0 = (int)x0f, y0 = (int)y0f;     // in [-1, 64]
        float gx = 1.f - fx, gy = 1.f - fy;
        float gym = gy * m, fym = fy * m;
        bool vx0 = (unsigned)x0 < 64u, vx1 = (unsigned)(x0 + 1) < 64u;
        bool vy0 = (unsigned)y0 < 64u, vy1 = (unsigned)(y0 + 1) < 64u;
        float w00 = (vy0 & vx0) ? gym * gx : 0.f;
        float w01 = (vy0 & vx1) ? gym * fx : 0.f;
        float w10 = (vy1 & vx0) ? fym * gx : 0.f;
        float w11 = (vy1 & vx1) ? fym * fx : 0.f;
        union { fp16x2v h; unsigned u; } p0u, p1u;
        p0u.h = __builtin_amdgcn_cvt_pkrtz(w00, w01);
        p1u.h = __builtin_amdgcn_cvt_pkrtz(w10, w11);
        wt[i] = uint2{p0u.u, p1u.u};
        xyt[i] = ((y0 << 6) + x0) * DALL;     // element offset of top-left corner
    }
    __syncthreads();

    // ---- phase 1: dcn, 4 slots per thread, offset-table-driven (no clamps) ----
    int ch8 = t & 7;
    #pragma unroll
    for (int iter = 0; iter < 4; ++iter) {
        int slotIdx = iter * 64 + (t >> 3);   // 0..255
        int px = slotIdx >> 2, g = slotIdx & 3;
        const unsigned short* vbase = vimg + g*64 + ch8*8;
        int tap0 = slotIdx * 9;

        half2v acc2[4] = {};
        #pragma unroll
        for (int k = 0; k < 9; ++k) {
            int off = xyt[tap0 + k];
            uint2 wp = wt[tap0 + k];
            const unsigned short* vb = vbase + off;
            int4 v00 = *reinterpret_cast<const int4*>(vb);
            int4 v01 = *reinterpret_cast<const int4*>(vb + DALL);
            int4 v10 = *reinterpret_cast<const int4*>(vb + (DALL << 6));
            int4 v11 = *reinterpret_cast<const int4*>(vb + (DALL << 6) + DALL);
            union { unsigned u; half2v h; } c0, c1;
            c0.u = wp.x; c1.u = wp.y;
            half2v w00s; w00s[0] = c0.h[0]; w00s[1] = c0.h[0];
            half2v w01s; w01s[0] = c0.h[1]; w01s[1] = c0.h[1];
            half2v w10s; w10s[0] = c1.h[0]; w10s[1] = c1.h[0];
            half2v w11s; w11s[0] = c1.h[1]; w11s[1] = c1.h[1];
            union { int4 i; half2v hp[4]; } u00, u01, u10, u11;
            u00.i = v00; u01.i = v01; u10.i = v10; u11.i = v11;
            #pragma unroll
            for (int q = 0; q < 4; ++q) acc2[q] = u00.hp[q] * w00s + acc2[q];
            #pragma unroll
            for (int q = 0; q < 4; ++q) acc2[q] = u01.hp[q] * w01s + acc2[q];
            #pragma unroll
            for (int q = 0; q < 4; ++q) acc2[q] = u10.hp[q] * w10s + acc2[q];
            #pragma unroll
            for (int q = 0; q < 4; ++q) acc2[q] = u11.hp[q] * w11s + acc2[q];
        }
        union { short8v s; half2v hp[4]; } ou;
        #pragma unroll
        for (int q = 0; q < 4; ++q) ou.hp[q] = acc2[q];
        // write into section g, row px, kg = ch8 (B-swizzled)
        *reinterpret_cast<short8v*>(
            &y_lds[g*4096 + px*64 + ((ch8 ^ (px & 7)) << 3)]) = ou.s;
    }

    // ---- phase 2: GEMM (M=256 d, N=64 px, K=256) ----
    int lane = t & 63;
    int wv = t >> 6;                          // 8 waves
    int wr = wv >> 1, wc = wv & 1;            // wr: 64-d band, wc: 32-px band
    int r_l = lane & 15, kg_l = lane >> 4;

    f32x4 acc[4][2] = {};
    for (int kt = 0; kt < 4; ++kt) {
        int c0 = kt * 64;
        __syncthreads();   // tap tables/As free (phase1 done or prior kt MFMA done)
        #pragma unroll
        for (int i = 0; i < 4; ++i) {
            int idx = t + i * 512;            // 2048 jobs: row 0..255, kg 0..7
            int row = idx >> 3, kg = idx & 7;
            *reinterpret_cast<short8v*>(&As[row*64 + ((kg ^ (row & 7)) << 3)]) =
                *reinterpret_cast<const short8v*>(&Wouth[(size_t)row*256 + c0 + kg*8]);
        }
        __syncthreads();
        #pragma unroll
        for (int ks = 0; ks < 2; ++ks) {
            half8v af[4], bfr[2];
            #pragma unroll
            for (int m = 0; m < 4; ++m) {
                int row = wr*64 + m*16 + r_l;
                af[m] = *reinterpret_cast<const half8v*>(
                    &As[row*64 + (((ks*4 + kg_l) ^ (row & 7)) << 3)]);
            }
            #pragma unroll
            for (int n = 0; n < 2; ++n) {
                int row = wc*32 + n*16 + r_l;
                bfr[n] = *reinterpret_cast<const half8v*>(
                    &y_lds[kt*4096 + row*64 + (((ks*4 + kg_l) ^ (row & 7)) << 3)]);
            }
            #pragma unroll
            for (int m = 0; m < 4; ++m)
                #pragma unroll
                for (int n = 0; n < 2; ++n)
                    acc[m][n] = __builtin_amdgcn_mfma_f32_16x16x32_f16(af[m], bfr[n], acc[m][n], 0, 0, 0);
        }
    }

    // ---- epilogue: bias + SiLU + NCHW f32 store ----
    #pragma unroll
    for (int m = 0; m < 4; ++m) {
        int dbase = wr*64 + m*16 + (kg_l << 2);
        #pragma unroll
        for (int r = 0; r < 4; ++r) {
            int d = dbase + r;
            float bb = bout[d];
            #pragma unroll
            for (int n = 0; n < 2; ++n) {
                int pcol = wc*32 + n*16 + r_l;
                float z = acc[m][n][r] + bb;
                float sv = z / (1.f + __expf(-z));
                out[((size_t)(nimg*256 + d))*4096 + hw0 + pcol] = sv;
            }
        }
    }
}

extern "C" void kernel_launch(void* const* d_in, const int* in_sizes, int n_in,
                              void* d_out, int out_size, void* d_ws, size_t ws_size,
                              hipStream_t stream) {
    const float* x       = (const float*)d_in[0];
    const float* cv1_w   = (const float*)d_in[1];
    const float* cv1_b   = (const float*)d_in[2];
    const float* value_w = (const float*)d_in[3];
    const float* value_b = (const float*)d_in[4];
    const float* dw_w    = (const float*)d_in[5];
    const float* dw_b    = (const float*)d_in[6];
    const float* om_w    = (const float*)d_in[7];
    const float* om_b    = (const float*)d_in[8];
    const float* out_w   = (const float*)d_in[9];
    const float* cv2_w   = (const float*)d_in[10];
    const float* bn_g    = (const float*)d_in[11];
    const float* bn_b    = (const float*)d_in[12];
    const float* bn_m    = (const float*)d_in[13];
    const float* bn_v    = (const float*)d_in[14];

    char* ws = (char*)d_ws;
    unsigned short* VOg    = (unsigned short*)(ws);
    unsigned short* VO     = VOg + GFRONT;
    unsigned short* Wallh  = (unsigned short*)(ws + 25317888);
    unsigned short* Wouth  = (unsigned short*)(ws + 25514496);
    float*          ball   = (float*)(ws + 25645568);
    float*          bout   = (float*)(ws + 25647104);
    float* out = (float*)d_out;

    prep_kernel<<<680, 256, 0, stream>>>(cv1_w, cv1_b, value_w, value_b, dw_w, dw_b,
                                         om_w, om_b, out_w, cv2_w,
                                         bn_g, bn_b, bn_m, bn_v,
                                         Wallh, ball, Wouth, bout, VOg);
    gemm_vo_kernel<<<dim3(3, 256), 256, 0, stream>>>(x, Wallh, ball, VO);
    dcn_gemm_kernel<<<512, 512, 0, stream>>>(VO, Wouth, bout, out);
}

// Round 25
// 78.083 us; speedup vs baseline: 1.0398x; 1.0398x over previous
//
#include <hip/hip_runtime.h>
#include <hip/hip_bf16.h>
#include <math.h>

#define NN    8
#define HH    64
#define WW    64
#define HW    4096
#define NHW   32768
#define DALL  384     // 256 value + 112 om + 16 pad
#define EPSBN 1e-5f
#define GFRONT 25344              // guard shorts before VO (>= 65*384=24960)
#define GBACK  50688              // guard shorts after VO (>= 49792)
#define VOELEMS 12582912          // NHW*384

typedef __attribute__((ext_vector_type(8))) short short8v;
typedef __attribute__((ext_vector_type(4))) float f32x4;
typedef __attribute__((ext_vector_type(2))) _Float16 half2v;
typedef __attribute__((ext_vector_type(8))) _Float16 half8v;
typedef __attribute__((ext_vector_type(2))) __fp16 fp16x2v;   // cvt_pkrtz return type

__device__ __forceinline__ unsigned short f2h(float f) {
    union { _Float16 h; unsigned short u; } c; c.h = (_Float16)f; return c.u;
}
__device__ __forceinline__ float h2f(unsigned short u) {
    union { unsigned short u; _Float16 h; } c; c.u = u; return (float)c.h;
}

// Workspace layout (bytes):
//  VOg    [GFRONT + NHW*384 + GBACK] f16 @ 0    (25317888)   VO = VOg+GFRONT
//  Wallh  [384][256] f16   @ 25317888   (196608)
//  Wouth  [256][256] f16   @ 25514496   (131072)
//  ball   [384] f32        @ 25645568   (1536)
//  bout   [256] f32        @ 25647104   (1024)

// ---------------- prep: fold weights (f32 math, f16 output) + guard zeroing ----------------
__global__ __launch_bounds__(256)
void prep_kernel(const float* __restrict__ cv1_w, const float* __restrict__ cv1_b,
                 const float* __restrict__ value_w, const float* __restrict__ value_b,
                 const float* __restrict__ dw_w, const float* __restrict__ dw_b,
                 const float* __restrict__ om_w, const float* __restrict__ om_b,
                 const float* __restrict__ out_w, const float* __restrict__ cv2_w,
                 const float* __restrict__ bn_g, const float* __restrict__ bn_b,
                 const float* __restrict__ bn_m, const float* __restrict__ bn_v,
                 unsigned short* __restrict__ Wallh, float* __restrict__ ball,
                 unsigned short* __restrict__ Wouth, float* __restrict__ bout,
                 unsigned short* __restrict__ VOg)
{
    int job = blockIdx.x * 256 + threadIdx.x;
    if (job < 65536) {                          // Wv = value_w @ cv1_w
        int d = job >> 8, cc = job & 255;
        float s0=0.f, s1=0.f, s2=0.f, s3=0.f;
        for (int e = 0; e < 256; e += 4) {
            float4 wv = *reinterpret_cast<const float4*>(&value_w[d*256+e]);
            s0 = fmaf(wv.x, cv1_w[(e+0)*256+cc], s0);
            s1 = fmaf(wv.y, cv1_w[(e+1)*256+cc], s1);
            s2 = fmaf(wv.z, cv1_w[(e+2)*256+cc], s2);
            s3 = fmaf(wv.w, cv1_w[(e+3)*256+cc], s3);
        }
        Wallh[job] = f2h((s0+s1)+(s2+s3));
    } else if (job < 94208) {                   // Wom = om_w.diag(dw_w) @ cv1_w
        int idx = job - 65536;
        int o = idx >> 8, cc = idx & 255;
        float s0=0.f, s1=0.f, s2=0.f, s3=0.f;
        for (int e = 0; e < 256; e += 4) {
            float4 wv = *reinterpret_cast<const float4*>(&om_w[o*256+e]);
            float4 dv = *reinterpret_cast<const float4*>(&dw_w[e]);
            s0 = fmaf(wv.x*dv.x, cv1_w[(e+0)*256+cc], s0);
            s1 = fmaf(wv.y*dv.y, cv1_w[(e+1)*256+cc], s1);
            s2 = fmaf(wv.z*dv.z, cv1_w[(e+2)*256+cc], s2);
            s3 = fmaf(wv.w*dv.w, cv1_w[(e+3)*256+cc], s3);
        }
        Wallh[job] = f2h((s0+s1)+(s2+s3));
    } else if (job < 98304) {                   // pad rows 368..383
        Wallh[job] = 0;
    } else if (job < 163840) {                  // Wout = diag(s) cv2_w @ out_w
        int idx = job - 98304;
        int d = idx >> 8, cc = idx & 255;
        float s0=0.f, s1=0.f, s2=0.f, s3=0.f;
        for (int e = 0; e < 256; e += 4) {
            float4 wv = *reinterpret_cast<const float4*>(&cv2_w[d*256+e]);
            s0 = fmaf(wv.x, out_w[(e+0)*256+cc], s0);
            s1 = fmaf(wv.y, out_w[(e+1)*256+cc], s1);
            s2 = fmaf(wv.z, out_w[(e+2)*256+cc], s2);
            s3 = fmaf(wv.w, out_w[(e+3)*256+cc], s3);
        }
        float sc = bn_g[d] * rsqrtf(bn_v[d] + EPSBN);
        Wouth[idx] = f2h(((s0+s1)+(s2+s3)) * sc);
    } else if (job < 164096) {                  // bv
        int d = job - 163840;
        float s = value_b[d];
        for (int e = 0; e < 256; ++e) s = fmaf(value_w[d*256+e], cv1_b[e], s);
        ball[d] = s;
    } else if (job < 164208) {                  // bom
        int o = job - 164096;
        float s = om_b[o];
        for (int e = 0; e < 256; ++e)
            s = fmaf(om_w[o*256+e], fmaf(dw_w[e], cv1_b[e], dw_b[e]), s);
        ball[256 + o] = s;
    } else if (job < 164224) {                  // ball pad
        ball[368 + job - 164208] = 0.f;
    } else if (job < 164480) {                  // bout
        int d = job - 164224;
        float sc = bn_g[d] * rsqrtf(bn_v[d] + EPSBN);
        bout[d] = fmaf(-bn_m[d], sc, bn_b[d]);
    } else if (job < 173984) {                  // zero VO guard margins (every call)
        int i = job - 164480;                   // 0..9503
        size_t dst = (i < 3168) ? (size_t)i * 8
                                : (size_t)GFRONT + VOELEMS + (size_t)(i - 3168) * 8;
        short8v z = {};
        *reinterpret_cast<short8v*>(&VOg[dst]) = z;
    }
}

// ---------------- GEMM1 (fused x-transpose): VO = f16(x)^T @ Wallh^T + ball ----------------
__global__ __launch_bounds__(256)
void gemm_vo_kernel(const float* __restrict__ x, const unsigned short* __restrict__ Wallh,
                    const float* __restrict__ ball, unsigned short* __restrict__ VO)
{
    __shared__ unsigned short As[8192];
    __shared__ unsigned short Bs[8192];
    int t = threadIdx.x;
    int m0 = blockIdx.y * 128;   // pixel tile
    int n0 = blockIdx.x * 128;   // output-channel tile
    int nimg = m0 >> 12, hw0 = m0 & 4095;
    int lane = t & 63;
    int wv = t >> 6;
    int wr = wv >> 1, wc = wv & 1;
    int r_l = lane & 15, kg_l = lane >> 4;
    int ci = t >> 6;             // c-chunk (16 ch) for A staging
    int l  = t & 63;             // row-pair for A staging

    const float* xbase = x + (size_t)(nimg * 256) * 4096 + hw0;

    f32x4 acc[4][4] = {};

    for (int kt = 0; kt < 4; ++kt) {
        int c0 = kt * 64;
        float2 val[16];
        #pragma unroll
        for (int i = 0; i < 16; ++i)
            val[i] = *reinterpret_cast<const float2*>(
                &xbase[(size_t)(c0 + ci*16 + i) * 4096 + 2*l]);
        __syncthreads();   // prior MFMA reads done before overwrite
        #pragma unroll
        for (int rsel = 0; rsel < 2; ++rsel) {
            int row = 2*l + rsel;
            #pragma unroll
            for (int kgi = 0; kgi < 2; ++kgi) {
                int kg = ci*2 + kgi;
                union { short8v s; fp16x2v h[4]; } su;
                #pragma unroll
                for (int j = 0; j < 8; j += 2) {
                    float a = rsel ? val[kgi*8+j].y   : val[kgi*8+j].x;
                    float b = rsel ? val[kgi*8+j+1].y : val[kgi*8+j+1].x;
                    su.h[j>>1] = __builtin_amdgcn_cvt_pkrtz(a, b);
                }
                *reinterpret_cast<short8v*>(&As[row*64 + ((kg ^ (row & 7)) << 3)]) = su.s;
            }
        }
        #pragma unroll
        for (int i = 0; i < 4; ++i) {
            int idx = t + i*256;
            int row = idx >> 3, kg = idx & 7;
            *reinterpret_cast<short8v*>(&Bs[row*64 + ((kg ^ (row & 7)) << 3)]) =
                *reinterpret_cast<const short8v*>(&Wallh[(size_t)(n0 + row)*256 + c0 + kg*8]);
        }
        __syncthreads();
        #pragma unroll
        for (int ks = 0; ks < 2; ++ks) {
            half8v af[4], bfr[4];
            #pragma unroll
            for (int m = 0; m < 4; ++m) {
                int row = wr*64 + m*16 + r_l;
                af[m] = *reinterpret_cast<const half8v*>(
                    &As[row*64 + (((ks*4 + kg_l) ^ (row & 7)) << 3)]);
            }
            #pragma unroll
            for (int n = 0; n < 4; ++n) {
                int row = wc*64 + n*16 + r_l;
                bfr[n] = *reinterpret_cast<const half8v*>(
                    &Bs[row*64 + (((ks*4 + kg_l) ^ (row & 7)) << 3)]);
            }
            #pragma unroll
            for (int m = 0; m < 4; ++m)
                #pragma unroll
                for (int n = 0; n < 4; ++n)
                    acc[m][n] = __builtin_amdgcn_mfma_f32_16x16x32_f16(af[m], bfr[n], acc[m][n], 0, 0, 0);
        }
    }

    #pragma unroll
    for (int n = 0; n < 4; ++n) {
        int d = n0 + wc*64 + n*16 + r_l;
        float bb = ball[d];
        #pragma unroll
        for (int m = 0; m < 4; ++m) {
            int pr = m0 + wr*64 + m*16 + (kg_l << 2);
            #pragma unroll
            for (int r = 0; r < 4; ++r)
                VO[(size_t)(pr + r)*384 + d] = f2h(acc[m][n][r] + bb);
        }
    }
}

// ---------------- fused DCNv4 + GEMM2: out = SiLU(Wout @ dcn(VO)^T + bout) ----------------
// Tap-table stores the precomputed corner OFFSET (no per-lane clamps):
// phase-0 clamps pxf/pyf to [-1,64] (equivalent to reference masking), OOB
// corner weights are exactly 0, and VO guard margins make the reads safe.
__global__ __launch_bounds__(512, 4)
void dcn_gemm_kernel(const unsigned short* __restrict__ VO,
                     const unsigned short* __restrict__ Wouth,
                     const float* __restrict__ bout, float* __restrict__ out)
{
    __shared__ unsigned short y_lds[16384];   // 32 KB: 4 sections x [64px][64k], swizzled
    __shared__ int u_buf_i[8192];             // 32 KB: tap tables | phase2 As
    int*   xyt = u_buf_i;                                    // [2304] corner element offset
    uint2* wt  = reinterpret_cast<uint2*>(u_buf_i + 2304);   // [2304] 4 f16 weights
    unsigned short* As = reinterpret_cast<unsigned short*>(u_buf_i);

    int t = threadIdx.x;
    int bid = blockIdx.x;                     // 512 blocks = 8 XCD x 64
    int logical = ((bid & 7) << 6) + (bid >> 3);   // image == XCD
    int p0 = logical * 64;
    int nimg = p0 >> 12;
    int hw0 = p0 & 4095;
    int h = hw0 >> 6;                         // single image row; w == px

    const unsigned short* vimg = VO + (size_t)nimg * (HW * (size_t)DALL);

    // ---- phase 0: build tap tables (setup math computed once per tap) ----
    for (int i = t; i < 2304; i += 512) {
        int px = i / 36;
        int rem = i - px * 36;
        int g = rem / 9;
        int k = rem - g * 9;
        const unsigned short* ob = vimg + (size_t)(hw0 + px) * DALL + 256 + g * 27;
        float dxo = h2f(ob[2*k]), dyo = h2f(ob[2*k+1]), m = h2f(ob[18+k]);
        float pxf = fminf(fmaxf((float)(px + (k % 3) - 1) + dxo, -1.f), 64.f);
        float pyf = fminf(fmaxf((float)(h  + (k / 3) - 1) + dyo, -1.f), 64.f);
        float x0f = floorf(pxf), y0f = floorf(pyf);
        float fx = pxf - x0f, fy = pyf - y0f;
        int x0 = (int)x0f, y0 = (int)y0f;     // in [-1, 64]
        float gx = 1.f - fx, gy = 1.f - fy;
        float gym = gy * m, fym = fy * m;
        bool vx0 = (unsigned)x0 < 64u, vx1 = (unsigned)(x0 + 1) < 64u;
        bool vy0 = (unsigned)y0 < 64u, vy1 = (unsigned)(y0 + 1) < 64u;
        float w00 = (vy0 & vx0) ? gym * gx : 0.f;
        float w01 = (vy0 & vx1) ? gym * fx : 0.f;
        float w10 = (vy1 & vx0) ? fym * gx : 0.f;
        float w11 = (vy1 & vx1) ? fym * fx : 0.f;
        union { fp16x2v h; unsigned u; } p0u, p1u;
        p0u.h = __builtin_amdgcn_cvt_pkrtz(w00, w01);
        p1u.h = __builtin_amdgcn_cvt_pkrtz(w10, w11);
        wt[i] = uint2{p0u.u, p1u.u};
        xyt[i] = ((y0 << 6) + x0) * DALL;     // element offset of top-left corner
    }
    __syncthreads();

    // ---- phase 1: dcn, 4 slots per thread, offset-table-driven (no clamps) ----
    int ch8 = t & 7;
    #pragma unroll
    for (int iter = 0; iter < 4; ++iter) {
        int slotIdx = iter * 64 + (t >> 3);   // 0..255
        int px = slotIdx >> 2, g = slotIdx & 3;
        const unsigned short* vbase = vimg + g*64 + ch8*8;
        int tap0 = slotIdx * 9;

        half2v acc2[4] = {};
        #pragma unroll
        for (int k = 0; k < 9; ++k) {
            int off = xyt[tap0 + k];
            uint2 wp = wt[tap0 + k];
            const unsigned short* vb = vbase + off;
            int4 v00 = *reinterpret_cast<const int4*>(vb);
            int4 v01 = *reinterpret_cast<const int4*>(vb + DALL);
            int4 v10 = *reinterpret_cast<const int4*>(vb + (DALL << 6));
            int4 v11 = *reinterpret_cast<const int4*>(vb + (DALL << 6) + DALL);
            union { unsigned u; half2v h; } c0, c1;
            c0.u = wp.x; c1.u = wp.y;
            half2v w00s; w00s[0] = c0.h[0]; w00s[1] = c0.h[0];
            half2v w01s; w01s[0] = c0.h[1]; w01s[1] = c0.h[1];
            half2v w10s; w10s[0] = c1.h[0]; w10s[1] = c1.h[0];
            half2v w11s; w11s[0] = c1.h[1]; w11s[1] = c1.h[1];
            union { int4 i; half2v hp[4]; } u00, u01, u10, u11;
            u00.i = v00; u01.i = v01; u10.i = v10; u11.i = v11;
            #pragma unroll
            for (int q = 0; q < 4; ++q) acc2[q] = u00.hp[q] * w00s + acc2[q];
            #pragma unroll
            for (int q = 0; q < 4; ++q) acc2[q] = u01.hp[q] * w01s + acc2[q];
            #pragma unroll
            for (int q = 0; q < 4; ++q) acc2[q] = u10.hp[q] * w10s + acc2[q];
            #pragma unroll
            for (int q = 0; q < 4; ++q) acc2[q] = u11.hp[q] * w11s + acc2[q];
        }
        union { short8v s; half2v hp[4]; } ou;
        #pragma unroll
        for (int q = 0; q < 4; ++q) ou.hp[q] = acc2[q];
        // write into section g, row px, kg = ch8 (B-swizzled)
        *reinterpret_cast<short8v*>(
            &y_lds[g*4096 + px*64 + ((ch8 ^ (px & 7)) << 3)]) = ou.s;
    }

    // ---- phase 2: GEMM (M=256 d, N=64 px, K=256) ----
    int lane = t & 63;
    int wv = t >> 6;                          // 8 waves
    int wr = wv >> 1, wc = wv & 1;            // wr: 64-d band, wc: 32-px band
    int r_l = lane & 15, kg_l = lane >> 4;

    f32x4 acc[4][2] = {};
    for (int kt = 0; kt < 4; ++kt) {
        int c0 = kt * 64;
        __syncthreads();   // tap tables/As free (phase1 done or prior kt MFMA done)
        #pragma unroll
        for (int i = 0; i < 4; ++i) {
            int idx = t + i * 512;            // 2048 jobs: row 0..255, kg 0..7
            int row = idx >> 3, kg = idx & 7;
            *reinterpret_cast<short8v*>(&As[row*64 + ((kg ^ (row & 7)) << 3)]) =
                *reinterpret_cast<const short8v*>(&Wouth[(size_t)row*256 + c0 + kg*8]);
        }
        __syncthreads();
        #pragma unroll
        for (int ks = 0; ks < 2; ++ks) {
            half8v af[4], bfr[2];
            #pragma unroll
            for (int m = 0; m < 4; ++m) {
                int row = wr*64 + m*16 + r_l;
                af[m] = *reinterpret_cast<const half8v*>(
                    &As[row*64 + (((ks*4 + kg_l) ^ (row & 7)) << 3)]);
            }
            #pragma unroll
            for (int n = 0; n < 2; ++n) {
                int row = wc*32 + n*16 + r_l;
                bfr[n] = *reinterpret_cast<const half8v*>(
                    &y_lds[kt*4096 + row*64 + (((ks*4 + kg_l) ^ (row & 7)) << 3)]);
            }
            #pragma unroll
            for (int m = 0; m < 4; ++m)
                #pragma unroll
                for (int n = 0; n < 2; ++n)
                    acc[m][n] = __builtin_amdgcn_mfma_f32_16x16x32_f16(af[m], bfr[n], acc[m][n], 0, 0, 0);
        }
    }

    // ---- epilogue: bias + SiLU + NCHW f32 store ----
    #pragma unroll
    for (int m = 0; m < 4; ++m) {
        int dbase = wr*64 + m*16 + (kg_l << 2);
        #pragma unroll
        for (int r = 0; r < 4; ++r) {
            int d = dbase + r;
            float bb = bout[d];
            #pragma unroll
            for (int n = 0; n < 2; ++n) {
                int pcol = wc*32 + n*16 + r_l;
                float z = acc[m][n][r] + bb;
                float sv = z / (1.f + __expf(-z));
                out[((size_t)(nimg*256 + d))*4096 + hw0 + pcol] = sv;
            }
        }
    }
}

extern "C" void kernel_launch(void* const* d_in, const int* in_sizes, int n_in,
                              void* d_out, int out_size, void* d_ws, size_t ws_size,
                              hipStream_t stream) {
    const float* x       = (const float*)d_in[0];
    const float* cv1_w   = (const float*)d_in[1];
    const float* cv1_b   = (const float*)d_in[2];
    const float* value_w = (const float*)d_in[3];
    const float* value_b = (const float*)d_in[4];
    const float* dw_w    = (const float*)d_in[5];
    const float* dw_b    = (const float*)d_in[6];
    const float* om_w    = (const float*)d_in[7];
    const float* om_b    = (const float*)d_in[8];
    const float* out_w   = (const float*)d_in[9];
    const float* cv2_w   = (const float*)d_in[10];
    const float* bn_g    = (const float*)d_in[11];
    const float* bn_b    = (const float*)d_in[12];
    const float* bn_m    = (const float*)d_in[13];
    const float* bn_v    = (const float*)d_in[14];

    char* ws = (char*)d_ws;
    unsigned short* VOg    = (unsigned short*)(ws);
    unsigned short* VO     = VOg + GFRONT;
    unsigned short* Wallh  = (unsigned short*)(ws + 25317888);
    unsigned short* Wouth  = (unsigned short*)(ws + 25514496);
    float*          ball   = (float*)(ws + 25645568);
    float*          bout   = (float*)(ws + 25647104);
    float* out = (float*)d_out;

    prep_kernel<<<680, 256, 0, stream>>>(cv1_w, cv1_b, value_w, value_b, dw_w, dw_b,
                                         om_w, om_b, out_w, cv2_w,
                                         bn_g, bn_b, bn_m, bn_v,
                                         Wallh, ball, Wouth, bout, VOg);
    gemm_vo_kernel<<<dim3(3, 256), 256, 0, stream>>>(x, Wallh, ball, VO);
    dcn_gemm_kernel<<<512, 512, 0, stream>>>(VO, Wouth, bout, out);
}